// Round 1
// baseline (32312.061 us; speedup 1.0000x reference)
//
#include <hip/hip_runtime.h>
#include <math.h>

// Problem dims
constexpr int NB = 256;    // batch
constexpr int NT = 64;     // T-1 steps
constexpr int DS = 128;    // state
constexpr int DA = 32;     // action
constexpr int DB = 1024;   // belief
constexpr int DH = 1024;   // hidden
constexpr int DE = 1024;   // embed
constexpr float MIN_STD = 0.1f;

// Output layout (floats), in reference return order
constexpr size_t OUT_BEL = 0;
constexpr size_t OUT_PS  = (size_t)NT * NB * DB;             // prior_states
constexpr size_t OUT_PM  = OUT_PS  + (size_t)NT * NB * DS;   // prior_means
constexpr size_t OUT_PSD = OUT_PM  + (size_t)NT * NB * DS;   // prior_stds
constexpr size_t OUT_QS  = OUT_PSD + (size_t)NT * NB * DS;   // post_states
constexpr size_t OUT_QM  = OUT_QS  + (size_t)NT * NB * DS;   // post_means
constexpr size_t OUT_QSD = OUT_QM  + (size_t)NT * NB * DS;   // post_stds

// ---------------------------------------------------------------------------
// K1: x = relu([state*nt, action] @ W_sa^T + b_sa)   -> ws.x [NB, DB]
// grid (4, NB), block 256: j = bx*256+tx, b = by
// ---------------------------------------------------------------------------
__global__ __launch_bounds__(256) void k_prep_x(
    const float* __restrict__ state, const float* __restrict__ act,
    const float* __restrict__ nt,
    const float* __restrict__ W_sa, const float* __restrict__ b_sa,
    float* __restrict__ x)
{
    __shared__ float sa[DS + DA];
    const int b  = blockIdx.y;
    const int tx = threadIdx.x;
    const float ntv = nt ? nt[b] : 1.0f;
    if (tx < DS)            sa[tx] = state[b * DS + tx] * ntv;
    else if (tx < DS + DA)  sa[tx] = act[b * DA + (tx - DS)];
    __syncthreads();
    const int j = blockIdx.x * 256 + tx;
    const float* w = W_sa + (size_t)j * (DS + DA);
    float acc = b_sa[j];
    #pragma unroll 8
    for (int k = 0; k < DS + DA; ++k) acc = fmaf(sa[k], w[k], acc);
    x[(size_t)b * DB + j] = fmaxf(acc, 0.0f);
}

// ---------------------------------------------------------------------------
// K2: GRU cell. gi = x@W_ih^T+b_ih ; gh = (belief*nt)@W_hh^T+b_hh ; combine.
// Writes nb directly into d_out beliefs[t].
// grid (32 j-tiles, 8 b-tiles), block 256. Tile 32x32, K-tile 32.
// ---------------------------------------------------------------------------
__global__ __launch_bounds__(256) void k_gru(
    const float* __restrict__ x, const float* __restrict__ bel_prev,
    const float* __restrict__ nt,
    const float* __restrict__ W_ih, const float* __restrict__ W_hh,
    const float* __restrict__ b_ih, const float* __restrict__ b_hh,
    float* __restrict__ nb_out)
{
    __shared__ float xs[32][33], hs[32][33];
    __shared__ float wir[32][33], wiz[32][33], win_[32][33];
    __shared__ float whr[32][33], whz[32][33], whn[32][33];
    __shared__ float nts[32];
    const int tx = threadIdx.x;
    const int jt = blockIdx.x, bt = blockIdx.y;
    const int jj = tx & 31, mg = tx >> 5;
    const int j = jt * 32 + jj;
    if (tx < 32) nts[tx] = nt ? nt[bt * 32 + tx] : 1.0f;
    __syncthreads();

    float air[4] = {}, aiz[4] = {}, ain_[4] = {};
    float ahr[4] = {}, ahz[4] = {}, ahn[4] = {};

    for (int kt = 0; kt < DB; kt += 32) {
        #pragma unroll
        for (int i = 0; i < 4; ++i) {
            const int idx = tx + i * 256;
            const int r = idx >> 5, c = idx & 31;
            const int gr = jt * 32 + r;
            xs[r][c]   = x[(size_t)(bt * 32 + r) * DB + kt + c];
            hs[r][c]   = bel_prev[(size_t)(bt * 32 + r) * DB + kt + c] * nts[r];
            wir[r][c]  = W_ih[(size_t)gr * DB + kt + c];
            wiz[r][c]  = W_ih[(size_t)(DB + gr) * DB + kt + c];
            win_[r][c] = W_ih[(size_t)(2 * DB + gr) * DB + kt + c];
            whr[r][c]  = W_hh[(size_t)gr * DB + kt + c];
            whz[r][c]  = W_hh[(size_t)(DB + gr) * DB + kt + c];
            whn[r][c]  = W_hh[(size_t)(2 * DB + gr) * DB + kt + c];
        }
        __syncthreads();
        #pragma unroll 8
        for (int k = 0; k < 32; ++k) {
            const float wr = wir[jj][k], wz = wiz[jj][k], wn = win_[jj][k];
            const float vr = whr[jj][k], vz = whz[jj][k], vn = whn[jj][k];
            #pragma unroll
            for (int m = 0; m < 4; ++m) {
                const float xv = xs[mg * 4 + m][k], hv = hs[mg * 4 + m][k];
                air[m]  = fmaf(xv, wr, air[m]);
                aiz[m]  = fmaf(xv, wz, aiz[m]);
                ain_[m] = fmaf(xv, wn, ain_[m]);
                ahr[m]  = fmaf(hv, vr, ahr[m]);
                ahz[m]  = fmaf(hv, vz, ahz[m]);
                ahn[m]  = fmaf(hv, vn, ahn[m]);
            }
        }
        __syncthreads();
    }

    const float bir = b_ih[j], biz = b_ih[DB + j], bin_ = b_ih[2 * DB + j];
    const float bhr = b_hh[j], bhz = b_hh[DB + j], bhn = b_hh[2 * DB + j];
    #pragma unroll
    for (int m = 0; m < 4; ++m) {
        const int b = bt * 32 + mg * 4 + m;
        const float hval = bel_prev[(size_t)b * DB + j] * nts[mg * 4 + m];
        const float r = 1.0f / (1.0f + expf(-(air[m] + bir + ahr[m] + bhr)));
        const float z = 1.0f / (1.0f + expf(-(aiz[m] + biz + ahz[m] + bhz)));
        const float n = tanhf(ain_[m] + bin_ + r * (ahn[m] + bhn));
        nb_out[(size_t)b * DB + j] = (1.0f - z) * n + z * hval;
    }
}

// ---------------------------------------------------------------------------
// K3: hp = relu(nb@W_bp^T + b_bp); hq = relu([nb,obs]@W_bq^T + b_bq)
// grid (32 j-tiles, 8 b-tiles), block 256.
// ---------------------------------------------------------------------------
__global__ __launch_bounds__(256) void k_heads_hidden(
    const float* __restrict__ nb, const float* __restrict__ obs,
    const float* __restrict__ W_bp, const float* __restrict__ b_bp,
    const float* __restrict__ W_bq, const float* __restrict__ b_bq,
    float* __restrict__ hp, float* __restrict__ hq)
{
    __shared__ float ns[32][33], wp[32][33], wq[32][33];
    const int tx = threadIdx.x;
    const int jt = blockIdx.x, bt = blockIdx.y;
    const int jj = tx & 31, mg = tx >> 5;
    const int j = jt * 32 + jj;
    float ap[4] = {}, aq[4] = {};

    for (int kt = 0; kt < DB; kt += 32) {
        #pragma unroll
        for (int i = 0; i < 4; ++i) {
            const int idx = tx + i * 256;
            const int r = idx >> 5, c = idx & 31;
            const int gr = jt * 32 + r;
            ns[r][c] = nb[(size_t)(bt * 32 + r) * DB + kt + c];
            wp[r][c] = W_bp[(size_t)gr * DB + kt + c];
            wq[r][c] = W_bq[(size_t)gr * (DB + DE) + kt + c];
        }
        __syncthreads();
        #pragma unroll 8
        for (int k = 0; k < 32; ++k) {
            const float a = wp[jj][k], q = wq[jj][k];
            #pragma unroll
            for (int m = 0; m < 4; ++m) {
                const float v = ns[mg * 4 + m][k];
                ap[m] = fmaf(v, a, ap[m]);
                aq[m] = fmaf(v, q, aq[m]);
            }
        }
        __syncthreads();
    }
    for (int kt = 0; kt < DE; kt += 32) {
        #pragma unroll
        for (int i = 0; i < 4; ++i) {
            const int idx = tx + i * 256;
            const int r = idx >> 5, c = idx & 31;
            const int gr = jt * 32 + r;
            ns[r][c] = obs[(size_t)(bt * 32 + r) * DE + kt + c];
            wq[r][c] = W_bq[(size_t)gr * (DB + DE) + DB + kt + c];
        }
        __syncthreads();
        #pragma unroll 8
        for (int k = 0; k < 32; ++k) {
            const float q = wq[jj][k];
            #pragma unroll
            for (int m = 0; m < 4; ++m)
                aq[m] = fmaf(ns[mg * 4 + m][k], q, aq[m]);
        }
        __syncthreads();
    }

    const float bp = b_bp[j], bq = b_bq[j];
    #pragma unroll
    for (int m = 0; m < 4; ++m) {
        const int b = bt * 32 + mg * 4 + m;
        hp[(size_t)b * DH + j] = fmaxf(ap[m] + bp, 0.0f);
        hq[(size_t)b * DH + j] = fmaxf(aq[m] + bq, 0.0f);
    }
}

// ---------------------------------------------------------------------------
// K4a: partial GEMMs for the 4 head outputs (pm, psd, qm, qsd).
// Virtual n in [0,256): n<128 -> prior head (input hp, W_sp); else post (hq, W_sq).
// K split into 4 chunks of 256 for occupancy. part: [kc][2][NB][256]
// grid (8 n-tiles, 8 b-tiles, 4 k-chunks), block 256.
// ---------------------------------------------------------------------------
__global__ __launch_bounds__(256) void k_heads_out_part(
    const float* __restrict__ hp, const float* __restrict__ hq,
    const float* __restrict__ W_sp, const float* __restrict__ W_sq,
    float* __restrict__ part)
{
    __shared__ float is_[32][33], wm[32][33], ws_[32][33];
    const int tx = threadIdx.x;
    const int ntile = blockIdx.x, bt = blockIdx.y, kc = blockIdx.z;
    const int jj = tx & 31, mg = tx >> 5;
    const int n = ntile * 32 + jj;
    const bool post = (ntile >= 4);
    const float* in = post ? hq : hp;
    const float* W  = post ? W_sq : W_sp;
    const int i0 = ntile * 32 - (post ? 128 : 0);

    float am[4] = {}, as[4] = {};
    const int k0 = kc * 256;
    for (int kt = k0; kt < k0 + 256; kt += 32) {
        #pragma unroll
        for (int i = 0; i < 4; ++i) {
            const int idx = tx + i * 256;
            const int r = idx >> 5, c = idx & 31;
            is_[r][c] = in[(size_t)(bt * 32 + r) * DH + kt + c];
            wm[r][c]  = W[(size_t)(i0 + r) * DH + kt + c];
            ws_[r][c] = W[(size_t)(128 + i0 + r) * DH + kt + c];
        }
        __syncthreads();
        #pragma unroll 8
        for (int k = 0; k < 32; ++k) {
            const float a = wm[jj][k], s = ws_[jj][k];
            #pragma unroll
            for (int m = 0; m < 4; ++m) {
                const float v = is_[mg * 4 + m][k];
                am[m] = fmaf(v, a, am[m]);
                as[m] = fmaf(v, s, as[m]);
            }
        }
        __syncthreads();
    }
    #pragma unroll
    for (int m = 0; m < 4; ++m) {
        const int b = bt * 32 + mg * 4 + m;
        part[(size_t)((kc * 2 + 0) * NB + b) * 256 + n] = am[m];
        part[(size_t)((kc * 2 + 1) * NB + b) * 256 + n] = as[m];
    }
}

// ---------------------------------------------------------------------------
// K4b: combine partials, softplus, sample, write all 6 small outputs.
// grid 256, block 256: idx over NB*256.
// ---------------------------------------------------------------------------
__global__ __launch_bounds__(256) void k_heads_out_fin(
    const float* __restrict__ part,
    const float* __restrict__ b_sp, const float* __restrict__ b_sq,
    const float* __restrict__ pn, const float* __restrict__ qn,
    float* __restrict__ o_ps, float* __restrict__ o_pm, float* __restrict__ o_psd,
    float* __restrict__ o_qs, float* __restrict__ o_qm, float* __restrict__ o_qsd)
{
    const int idx = blockIdx.x * 256 + threadIdx.x;
    const int b = idx >> 8;
    const int n = idx & 255;
    float m_ = 0.0f, s_ = 0.0f;
    #pragma unroll
    for (int c = 0; c < 4; ++c) {
        m_ += part[(size_t)((c * 2 + 0) * NB + b) * 256 + n];
        s_ += part[(size_t)((c * 2 + 1) * NB + b) * 256 + n];
    }
    const bool post = (n >= 128);
    const int i = n & 127;
    const float* bb = post ? b_sq : b_sp;
    const float mean = m_ + bb[i];
    const float sraw = s_ + bb[128 + i];
    const float sd = log1pf(expf(-fabsf(sraw))) + fmaxf(sraw, 0.0f) + MIN_STD;
    if (!post) {
        const float noise = pn[(size_t)b * DS + i];
        o_pm[(size_t)b * DS + i]  = mean;
        o_psd[(size_t)b * DS + i] = sd;
        o_ps[(size_t)b * DS + i]  = mean + sd * noise;
    } else {
        const float noise = qn[(size_t)b * DS + i];
        o_qm[(size_t)b * DS + i]  = mean;
        o_qsd[(size_t)b * DS + i] = sd;
        o_qs[(size_t)b * DS + i]  = mean + sd * noise;
    }
}

// ---------------------------------------------------------------------------
extern "C" void kernel_launch(void* const* d_in, const int* in_sizes, int n_in,
                              void* d_out, int out_size, void* d_ws, size_t ws_size,
                              hipStream_t stream)
{
    const float* prev_state  = (const float*)d_in[0];
    const float* actions     = (const float*)d_in[1];
    const float* prev_belief = (const float*)d_in[2];
    const float* observations= (const float*)d_in[3];
    const float* nonterm     = (const float*)d_in[4];
    const float* prior_noise = (const float*)d_in[5];
    const float* post_noise  = (const float*)d_in[6];
    const float* W_sa = (const float*)d_in[7];
    const float* b_sa = (const float*)d_in[8];
    const float* W_ih = (const float*)d_in[9];
    const float* W_hh = (const float*)d_in[10];
    const float* b_ih = (const float*)d_in[11];
    const float* b_hh = (const float*)d_in[12];
    const float* W_bp = (const float*)d_in[13];
    const float* b_bp = (const float*)d_in[14];
    const float* W_sp = (const float*)d_in[15];
    const float* b_sp = (const float*)d_in[16];
    const float* W_bq = (const float*)d_in[17];
    const float* b_bq = (const float*)d_in[18];
    const float* W_sq = (const float*)d_in[19];
    const float* b_sq = (const float*)d_in[20];

    float* out      = (float*)d_out;
    float* beliefs  = out + OUT_BEL;
    float* o_ps     = out + OUT_PS;
    float* o_pm     = out + OUT_PM;
    float* o_psd    = out + OUT_PSD;
    float* o_qs     = out + OUT_QS;
    float* o_qm     = out + OUT_QM;
    float* o_qsd    = out + OUT_QSD;

    float* ws  = (float*)d_ws;
    float* x   = ws;                       // NB*DB
    float* hp  = x  + (size_t)NB * DB;     // NB*DH
    float* hq  = hp + (size_t)NB * DH;     // NB*DH
    float* part= hq + (size_t)NB * DH;     // 4*2*NB*256 = 524288

    for (int t = 0; t < NT; ++t) {
        const float* nt  = (t == 0) ? nullptr : nonterm + (size_t)(t - 1) * NB;
        const float* st  = (t == 0) ? prev_state  : o_qs    + (size_t)(t - 1) * NB * DS;
        const float* bel = (t == 0) ? prev_belief : beliefs + (size_t)(t - 1) * NB * DB;
        float* nb = beliefs + (size_t)t * NB * DB;

        k_prep_x<<<dim3(4, NB), 256, 0, stream>>>(
            st, actions + (size_t)t * NB * DA, nt, W_sa, b_sa, x);

        k_gru<<<dim3(32, 8), 256, 0, stream>>>(
            x, bel, nt, W_ih, W_hh, b_ih, b_hh, nb);

        k_heads_hidden<<<dim3(32, 8), 256, 0, stream>>>(
            nb, observations + (size_t)t * NB * DE, W_bp, b_bp, W_bq, b_bq, hp, hq);

        k_heads_out_part<<<dim3(8, 8, 4), 256, 0, stream>>>(
            hp, hq, W_sp, W_sq, part);

        k_heads_out_fin<<<dim3(256), 256, 0, stream>>>(
            part, b_sp, b_sq,
            prior_noise + (size_t)t * NB * DS, post_noise + (size_t)t * NB * DS,
            o_ps + (size_t)t * NB * DS, o_pm + (size_t)t * NB * DS, o_psd + (size_t)t * NB * DS,
            o_qs + (size_t)t * NB * DS, o_qm + (size_t)t * NB * DS, o_qsd + (size_t)t * NB * DS);
    }
}

// Round 2
// 6705.014 us; speedup vs baseline: 4.8191x; 4.8191x over previous
//
#include <hip/hip_runtime.h>
#include <math.h>

// Problem dims
constexpr int NB = 256;    // batch
constexpr int NT = 64;     // T-1 steps
constexpr int DS = 128;    // state
constexpr int DA = 32;     // action
constexpr int DB = 1024;   // belief
constexpr int DH = 1024;   // hidden
constexpr int DE = 1024;   // embed
constexpr float MIN_STD = 0.1f;

// Output layout (floats), reference return order
constexpr size_t OUT_BEL = 0;
constexpr size_t OUT_PS  = (size_t)NT * NB * DB;
constexpr size_t OUT_PM  = OUT_PS  + (size_t)NT * NB * DS;
constexpr size_t OUT_PSD = OUT_PM  + (size_t)NT * NB * DS;
constexpr size_t OUT_QS  = OUT_PSD + (size_t)NT * NB * DS;
constexpr size_t OUT_QM  = OUT_QS  + (size_t)NT * NB * DS;
constexpr size_t OUT_QSD = OUT_QM  + (size_t)NT * NB * DS;

typedef __attribute__((ext_vector_type(8))) short bf8_t;   // 8 bf16 (4 VGPRs)
typedef __attribute__((ext_vector_type(4))) float f4_t;    // MFMA C/D frag

#define MFMA16(a, b, c) __builtin_amdgcn_mfma_f32_16x16x32_bf16((a), (b), (c), 0, 0, 0)
#define SWZ(row, ch) ((ch) ^ ((row) & 7))

__device__ __forceinline__ short f2bf(float f) {
    union { float f; unsigned u; } v; v.f = f;
    unsigned r = v.u + 0x7FFF + ((v.u >> 16) & 1);   // RNE
    return (short)(r >> 16);
}
__device__ __forceinline__ float sigm(float x) { return 1.0f / (1.0f + __expf(-x)); }

// ---------------------------------------------------------------------------
// Convert f32 -> bf16, 8 elems/thread
// ---------------------------------------------------------------------------
__global__ __launch_bounds__(256) void k_cvt(const float* __restrict__ src,
                                             short* __restrict__ dst, int n8) {
    int i = blockIdx.x * 256 + threadIdx.x;
    if (i >= n8) return;
    const float4* s4 = (const float4*)src;
    float4 a = s4[i * 2], b = s4[i * 2 + 1];
    bf8_t v;
    v[0] = f2bf(a.x); v[1] = f2bf(a.y); v[2] = f2bf(a.z); v[3] = f2bf(a.w);
    v[4] = f2bf(b.x); v[5] = f2bf(b.y); v[6] = f2bf(b.z); v[7] = f2bf(b.w);
    ((bf8_t*)dst)[i] = v;
}

// ---------------------------------------------------------------------------
// K1: x = relu([state*nt, action] @ W_sa^T + b_sa) -> x_bf (bf16)
// grid (4, NB), block 256
// ---------------------------------------------------------------------------
__global__ __launch_bounds__(256) void k_prep_x(
    const float* __restrict__ state, const float* __restrict__ act,
    const float* __restrict__ nt,
    const float* __restrict__ W_sa, const float* __restrict__ b_sa,
    short* __restrict__ x_bf)
{
    __shared__ float sa[DS + DA];
    const int b  = blockIdx.y;
    const int tx = threadIdx.x;
    const float ntv = nt ? nt[b] : 1.0f;
    if (tx < DS)            sa[tx] = state[b * DS + tx] * ntv;
    else if (tx < DS + DA)  sa[tx] = act[b * DA + (tx - DS)];
    __syncthreads();
    const int j = blockIdx.x * 256 + tx;
    const float* w = W_sa + (size_t)j * (DS + DA);
    float acc = b_sa[j];
    #pragma unroll 8
    for (int k = 0; k < DS + DA; ++k) acc = fmaf(sa[k], w[k], acc);
    x_bf[(size_t)b * DB + j] = f2bf(fmaxf(acc, 0.0f));
}

// ---------------------------------------------------------------------------
// K2: GRU via MFMA. Block tile: 64 batch x 32 j-cols x 6 gates, K=1024.
// grid (32 j-tiles, 4 b-tiles), block 256 (4 waves, 2m x 2n).
// Epilogue fuses gate math; writes beliefs[t] (f32) + nb_bf (bf16).
// ---------------------------------------------------------------------------
__global__ __launch_bounds__(256, 2) void k_gru_mfma(
    const short* __restrict__ x_bf, const float* __restrict__ bel_prev,
    const float* __restrict__ ntp,
    const short* __restrict__ wih_bf, const short* __restrict__ whh_bf,
    const float* __restrict__ b_ih, const float* __restrict__ b_hh,
    float* __restrict__ nb_out, short* __restrict__ nb_bf)
{
    __shared__ bf8_t Ax[64 * 8];      // x tile   [64 rows][64 k]
    __shared__ bf8_t Ah[64 * 8];      // h tile
    __shared__ bf8_t Bw[6 * 32 * 8];  // 6 gates x 32 rows x 64 k

    const int tx = threadIdx.x;
    const int wave = tx >> 6, lane = tx & 63;
    const int wm = wave & 1, wn = wave >> 1;
    const int jt = blockIdx.x, bt = blockIdx.y;
    const int j0 = jt * 32, b0 = bt * 64;

    const bf8_t* x8   = (const bf8_t*)x_bf;
    const bf8_t* wih8 = (const bf8_t*)wih_bf;
    const bf8_t* whh8 = (const bf8_t*)whh_bf;
    const float4* bp4 = (const float4*)bel_prev;

    f4_t acc[6][2];
    #pragma unroll
    for (int g = 0; g < 6; ++g)
        #pragma unroll
        for (int mi = 0; mi < 2; ++mi) acc[g][mi] = (f4_t)0.0f;

    for (int kt = 0; kt < DB; kt += 64) {
        // --- stage A tiles (x + h) : 2 chunks each per thread
        #pragma unroll
        for (int i = 0; i < 2; ++i) {
            const int c = tx + i * 256;          // 0..511
            const int row = c >> 3, ch = c & 7;
            const int gb = b0 + row;
            Ax[row * 8 + SWZ(row, ch)] = x8[(size_t)gb * 128 + (kt >> 3) + ch];
            const int fb = ((size_t)0, (gb * DB + kt + ch * 8)) >> 2;
            float4 f0 = bp4[fb], f1 = bp4[fb + 1];
            const float ntv = ntp ? ntp[gb] : 1.0f;
            bf8_t v;
            v[0] = f2bf(f0.x * ntv); v[1] = f2bf(f0.y * ntv);
            v[2] = f2bf(f0.z * ntv); v[3] = f2bf(f0.w * ntv);
            v[4] = f2bf(f1.x * ntv); v[5] = f2bf(f1.y * ntv);
            v[6] = f2bf(f1.z * ntv); v[7] = f2bf(f1.w * ntv);
            Ah[row * 8 + SWZ(row, ch)] = v;
        }
        // --- stage B tiles (6 gate weight slabs): 6 chunks per thread
        #pragma unroll
        for (int i = 0; i < 6; ++i) {
            const int c = tx + i * 256;          // 0..1535
            const int g = c >> 8;                // gate 0..5
            const int r = (c >> 3) & 31, ch = c & 7;
            const bf8_t* W = (g < 3) ? wih8 : whh8;
            const int grow = (g % 3) * DB + j0 + r;
            Bw[(g * 32 + r) * 8 + SWZ(r, ch)] = W[(size_t)grow * 128 + (kt >> 3) + ch];
        }
        __syncthreads();
        // --- compute
        #pragma unroll
        for (int ks = 0; ks < 2; ++ks) {
            const int ch = ks * 4 + (lane >> 4);
            bf8_t ax[2], ah[2], bw[6];
            #pragma unroll
            for (int mi = 0; mi < 2; ++mi) {
                const int row = wm * 32 + mi * 16 + (lane & 15);
                ax[mi] = Ax[row * 8 + SWZ(row, ch)];
                ah[mi] = Ah[row * 8 + SWZ(row, ch)];
            }
            #pragma unroll
            for (int g = 0; g < 6; ++g) {
                const int r = wn * 16 + (lane & 15);
                bw[g] = Bw[(g * 32 + r) * 8 + SWZ(r, ch)];
            }
            #pragma unroll
            for (int g = 0; g < 3; ++g) {
                #pragma unroll
                for (int mi = 0; mi < 2; ++mi) {
                    acc[g][mi]     = MFMA16(ax[mi], bw[g],     acc[g][mi]);
                    acc[g + 3][mi] = MFMA16(ah[mi], bw[g + 3], acc[g + 3][mi]);
                }
            }
        }
        __syncthreads();
    }

    // --- epilogue: gate math in f32, carry path in f32
    const int j = j0 + wn * 16 + (lane & 15);
    const float bir = b_ih[j], biz = b_ih[DB + j], bin = b_ih[2 * DB + j];
    const float bhr = b_hh[j], bhz = b_hh[DB + j], bhn = b_hh[2 * DB + j];
    #pragma unroll
    for (int mi = 0; mi < 2; ++mi) {
        #pragma unroll
        for (int r = 0; r < 4; ++r) {
            const int b = b0 + wm * 32 + mi * 16 + (lane >> 4) * 4 + r;
            const float ntv = ntp ? ntp[b] : 1.0f;
            const float hf = bel_prev[(size_t)b * DB + j] * ntv;
            const float rr = sigm(acc[0][mi][r] + bir + acc[3][mi][r] + bhr);
            const float zz = sigm(acc[1][mi][r] + biz + acc[4][mi][r] + bhz);
            const float nn = tanhf(acc[2][mi][r] + bin + rr * (acc[5][mi][r] + bhn));
            const float nb = (1.0f - zz) * nn + zz * hf;
            nb_out[(size_t)b * DB + j] = nb;
            nb_bf[(size_t)b * DB + j]  = f2bf(nb);
        }
    }
}

// ---------------------------------------------------------------------------
// K3: heads hidden. Virtual n-tiles: 0..15 -> hp (K=1024), 16..31 -> hq (K=2048).
// Block tile 64x64, grid (32, 4), block 256 (4 waves, 2m x 2n).
// ---------------------------------------------------------------------------
__global__ __launch_bounds__(256, 2) void k_heads_mfma(
    const short* __restrict__ nb_bf, const float* __restrict__ obs,
    const short* __restrict__ wbp_bf, const short* __restrict__ wbq_bf,
    const float* __restrict__ b_bp, const float* __restrict__ b_bq,
    short* __restrict__ hp_bf, short* __restrict__ hq_bf)
{
    __shared__ bf8_t Ab[64 * 8];
    __shared__ bf8_t Bb[64 * 8];

    const int tx = threadIdx.x;
    const int wave = tx >> 6, lane = tx & 63;
    const int wm = wave & 1, wn = wave >> 1;
    const int nt_ = blockIdx.x, bt = blockIdx.y;
    const bool isQ = nt_ >= 16;
    const int j0 = (nt_ & 15) * 64, b0 = bt * 64;
    const int K = isQ ? (DB + DE) : DB;
    const int ldc = isQ ? 256 : 128;   // weight row length in 8-elem chunks

    const bf8_t* nb8 = (const bf8_t*)nb_bf;
    const bf8_t* W8  = isQ ? (const bf8_t*)wbq_bf : (const bf8_t*)wbp_bf;
    const float4* o4 = (const float4*)obs;

    f4_t acc[2][2];
    #pragma unroll
    for (int mi = 0; mi < 2; ++mi)
        #pragma unroll
        for (int ni = 0; ni < 2; ++ni) acc[mi][ni] = (f4_t)0.0f;

    for (int kt = 0; kt < K; kt += 64) {
        #pragma unroll
        for (int i = 0; i < 2; ++i) {
            const int c = tx + i * 256;
            const int row = c >> 3, ch = c & 7;
            const int kk = kt + ch * 8;
            bf8_t v;
            if (!isQ || kk < DB) {
                v = nb8[(size_t)(b0 + row) * 128 + (kk >> 3)];
            } else {
                const int fb = ((b0 + row) * DE + (kk - DB)) >> 2;
                float4 f0 = o4[fb], f1 = o4[fb + 1];
                v[0] = f2bf(f0.x); v[1] = f2bf(f0.y); v[2] = f2bf(f0.z); v[3] = f2bf(f0.w);
                v[4] = f2bf(f1.x); v[5] = f2bf(f1.y); v[6] = f2bf(f1.z); v[7] = f2bf(f1.w);
            }
            Ab[row * 8 + SWZ(row, ch)] = v;
            Bb[row * 8 + SWZ(row, ch)] = W8[(size_t)(j0 + row) * ldc + (kt >> 3) + ch];
        }
        __syncthreads();
        #pragma unroll
        for (int ks = 0; ks < 2; ++ks) {
            const int ch = ks * 4 + (lane >> 4);
            bf8_t a[2], b[2];
            #pragma unroll
            for (int mi = 0; mi < 2; ++mi) {
                const int row = wm * 32 + mi * 16 + (lane & 15);
                a[mi] = Ab[row * 8 + SWZ(row, ch)];
            }
            #pragma unroll
            for (int ni = 0; ni < 2; ++ni) {
                const int row = wn * 32 + ni * 16 + (lane & 15);
                b[ni] = Bb[row * 8 + SWZ(row, ch)];
            }
            #pragma unroll
            for (int mi = 0; mi < 2; ++mi)
                #pragma unroll
                for (int ni = 0; ni < 2; ++ni)
                    acc[mi][ni] = MFMA16(a[mi], b[ni], acc[mi][ni]);
        }
        __syncthreads();
    }

    short* outp = isQ ? hq_bf : hp_bf;
    const float* bias = isQ ? b_bq : b_bp;
    #pragma unroll
    for (int ni = 0; ni < 2; ++ni) {
        const int j = j0 + wn * 32 + ni * 16 + (lane & 15);
        const float bj = bias[j];
        #pragma unroll
        for (int mi = 0; mi < 2; ++mi) {
            #pragma unroll
            for (int r = 0; r < 4; ++r) {
                const int m = b0 + wm * 32 + mi * 16 + (lane >> 4) * 4 + r;
                outp[(size_t)m * DH + j] = f2bf(fmaxf(acc[mi][ni][r] + bj, 0.0f));
            }
        }
    }
}

// ---------------------------------------------------------------------------
// K4: head outputs. Block: 32 batch x (32 means + 32 stds) for one head.
// grid (8 n-tiles [head*4 + i-tile], 8 b-tiles), block 256 (4 waves over n).
// Fused softplus + sampling epilogue via LDS exchange.
// ---------------------------------------------------------------------------
__global__ __launch_bounds__(256, 2) void k_out_mfma(
    const short* __restrict__ hp_bf, const short* __restrict__ hq_bf,
    const short* __restrict__ wsp_bf, const short* __restrict__ wsq_bf,
    const float* __restrict__ b_sp, const float* __restrict__ b_sq,
    const float* __restrict__ pn, const float* __restrict__ qn,
    float* __restrict__ o_ps, float* __restrict__ o_pm, float* __restrict__ o_psd,
    float* __restrict__ o_qs, float* __restrict__ o_qm, float* __restrict__ o_qsd)
{
    __shared__ bf8_t Ab[32 * 8];
    __shared__ bf8_t Bb[64 * 8];
    __shared__ float ebuf[32][65];

    const int tx = threadIdx.x;
    const int wave = tx >> 6, lane = tx & 63;
    const int wn = wave;
    const int nt_ = blockIdx.x, bt = blockIdx.y;
    const int head = nt_ >> 2, i0 = (nt_ & 3) * 32;
    const int b0 = bt * 32;

    const bf8_t* A8 = head ? (const bf8_t*)hq_bf : (const bf8_t*)hp_bf;
    const bf8_t* W8 = head ? (const bf8_t*)wsq_bf : (const bf8_t*)wsp_bf;

    f4_t acc[2];
    acc[0] = (f4_t)0.0f; acc[1] = (f4_t)0.0f;

    for (int kt = 0; kt < DH; kt += 64) {
        {   // A: 1 chunk per thread (32x64 tile)
            const int row = tx >> 3, ch = tx & 7;
            Ab[row * 8 + SWZ(row, ch)] = A8[(size_t)(b0 + row) * 128 + (kt >> 3) + ch];
        }
        #pragma unroll
        for (int i = 0; i < 2; ++i) {   // B: 2 chunks per thread (64x64)
            const int c = tx + i * 256;
            const int r = c >> 3, ch = c & 7;
            const int wr = (r < 32) ? (i0 + r) : (128 + i0 + (r - 32));
            Bb[r * 8 + SWZ(r, ch)] = W8[(size_t)wr * 128 + (kt >> 3) + ch];
        }
        __syncthreads();
        #pragma unroll
        for (int ks = 0; ks < 2; ++ks) {
            const int ch = ks * 4 + (lane >> 4);
            bf8_t a[2], b;
            #pragma unroll
            for (int mi = 0; mi < 2; ++mi) {
                const int row = mi * 16 + (lane & 15);
                a[mi] = Ab[row * 8 + SWZ(row, ch)];
            }
            {
                const int row = wn * 16 + (lane & 15);
                b = Bb[row * 8 + SWZ(row, ch)];
            }
            acc[0] = MFMA16(a[0], b, acc[0]);
            acc[1] = MFMA16(a[1], b, acc[1]);
        }
        __syncthreads();
    }

    #pragma unroll
    for (int mi = 0; mi < 2; ++mi)
        #pragma unroll
        for (int r = 0; r < 4; ++r)
            ebuf[mi * 16 + (lane >> 4) * 4 + r][wn * 16 + (lane & 15)] = acc[mi][r];
    __syncthreads();

    const float* bias = head ? b_sq : b_sp;
    const float* noise = head ? qn : pn;
    float* om  = head ? o_qm  : o_pm;
    float* osd = head ? o_qsd : o_psd;
    float* os  = head ? o_qs  : o_ps;
    #pragma unroll
    for (int i = 0; i < 4; ++i) {
        const int p = tx + i * 256;
        const int bl = p >> 5, il = p & 31;
        const float mean = ebuf[bl][il] + bias[i0 + il];
        const float sraw = ebuf[bl][il + 32] + bias[128 + i0 + il];
        const float sd = log1pf(__expf(-fabsf(sraw))) + fmaxf(sraw, 0.0f) + MIN_STD;
        const int b = b0 + bl, ii = i0 + il;
        om[(size_t)b * DS + ii]  = mean;
        osd[(size_t)b * DS + ii] = sd;
        os[(size_t)b * DS + ii]  = mean + sd * noise[(size_t)b * DS + ii];
    }
}

// ---------------------------------------------------------------------------
extern "C" void kernel_launch(void* const* d_in, const int* in_sizes, int n_in,
                              void* d_out, int out_size, void* d_ws, size_t ws_size,
                              hipStream_t stream)
{
    const float* prev_state  = (const float*)d_in[0];
    const float* actions     = (const float*)d_in[1];
    const float* prev_belief = (const float*)d_in[2];
    const float* observations= (const float*)d_in[3];
    const float* nonterm     = (const float*)d_in[4];
    const float* prior_noise = (const float*)d_in[5];
    const float* post_noise  = (const float*)d_in[6];
    const float* W_sa = (const float*)d_in[7];
    const float* b_sa = (const float*)d_in[8];
    const float* W_ih = (const float*)d_in[9];
    const float* W_hh = (const float*)d_in[10];
    const float* b_ih = (const float*)d_in[11];
    const float* b_hh = (const float*)d_in[12];
    const float* W_bp = (const float*)d_in[13];
    const float* b_bp = (const float*)d_in[14];
    const float* W_sp = (const float*)d_in[15];
    const float* b_sp = (const float*)d_in[16];
    const float* W_bq = (const float*)d_in[17];
    const float* b_bq = (const float*)d_in[18];
    const float* W_sq = (const float*)d_in[19];
    const float* b_sq = (const float*)d_in[20];

    float* out      = (float*)d_out;
    float* beliefs  = out + OUT_BEL;
    float* o_ps     = out + OUT_PS;
    float* o_pm     = out + OUT_PM;
    float* o_psd    = out + OUT_PSD;
    float* o_qs     = out + OUT_QS;
    float* o_qm     = out + OUT_QM;
    float* o_qsd    = out + OUT_QSD;

    // bf16 workspace layout (shorts)
    short* w = (short*)d_ws;
    short* wih_bf = w;                          // 3072*1024
    short* whh_bf = wih_bf + (size_t)3072 * 1024;
    short* wbp_bf = whh_bf + (size_t)3072 * 1024;   // 1024*1024
    short* wbq_bf = wbp_bf + (size_t)1024 * 1024;   // 1024*2048
    short* wsp_bf = wbq_bf + (size_t)1024 * 2048;   // 256*1024
    short* wsq_bf = wsp_bf + (size_t)256 * 1024;    // 256*1024
    short* x_bf   = wsq_bf + (size_t)256 * 1024;    // 256*1024
    short* nb_bf  = x_bf   + (size_t)NB * DB;
    short* hp_bf  = nb_bf  + (size_t)NB * DB;
    short* hq_bf  = hp_bf  + (size_t)NB * DH;

    // --- one-time (per call) weight conversion to bf16
    auto cvt = [&](const float* s, short* d, size_t n) {
        int n8 = (int)(n / 8);
        k_cvt<<<(n8 + 255) / 256, 256, 0, stream>>>(s, d, n8);
    };
    cvt(W_ih, wih_bf, (size_t)3072 * 1024);
    cvt(W_hh, whh_bf, (size_t)3072 * 1024);
    cvt(W_bp, wbp_bf, (size_t)1024 * 1024);
    cvt(W_bq, wbq_bf, (size_t)1024 * 2048);
    cvt(W_sp, wsp_bf, (size_t)256 * 1024);
    cvt(W_sq, wsq_bf, (size_t)256 * 1024);

    for (int t = 0; t < NT; ++t) {
        const float* nt  = (t == 0) ? nullptr : nonterm + (size_t)(t - 1) * NB;
        const float* st  = (t == 0) ? prev_state  : o_qs    + (size_t)(t - 1) * NB * DS;
        const float* bel = (t == 0) ? prev_belief : beliefs + (size_t)(t - 1) * NB * DB;
        float* nb = beliefs + (size_t)t * NB * DB;

        k_prep_x<<<dim3(4, NB), 256, 0, stream>>>(
            st, actions + (size_t)t * NB * DA, nt, W_sa, b_sa, x_bf);

        k_gru_mfma<<<dim3(32, 4), 256, 0, stream>>>(
            x_bf, bel, nt, wih_bf, whh_bf, b_ih, b_hh, nb, nb_bf);

        k_heads_mfma<<<dim3(32, 4), 256, 0, stream>>>(
            nb_bf, observations + (size_t)t * NB * DE,
            wbp_bf, wbq_bf, b_bp, b_bq, hp_bf, hq_bf);

        k_out_mfma<<<dim3(8, 8), 256, 0, stream>>>(
            hp_bf, hq_bf, wsp_bf, wsq_bf, b_sp, b_sq,
            prior_noise + (size_t)t * NB * DS, post_noise + (size_t)t * NB * DS,
            o_ps + (size_t)t * NB * DS, o_pm + (size_t)t * NB * DS, o_psd + (size_t)t * NB * DS,
            o_qs + (size_t)t * NB * DS, o_qm + (size_t)t * NB * DS, o_qsd + (size_t)t * NB * DS);
    }
}